// Round 15
// baseline (67.111 us; speedup 1.0000x reference)
//
#include <hip/hip_runtime.h>
#include <stdint.h>

// CapsuleLayer dynamic routing — round 15: cut K1 VMEM instruction count.
// x: [B=256, R=1152, I=8] f32; W: [C=10, R=1152, I=8, O=16] f32
// out: v = [B, C, 1, 1, O=16] f32
//
// r14 falsified the W-reload theory (asm-pinned W: identical 41.6us). The
// model that fits ALL rounds (r8/r9 float2 2x blowup at same FETCH; r14
// null; fillBuffer 6.6TB/s) is a per-CU VMEM-issue/TA-throughput limit.
// K1 had 32 VMEM instr/thread: 16 x-loads (4-way redundant across the oq
// quad) + 8 W + 8 narrow 8B stores. This round: 20 VMEM/thread:
//  - x tile (8 b x 128 r x 32B = 32KB) staged in LDS with 8 coalesced
//    dwordx4 loads; compute reads x via LDS (separate pipe, broadcast).
//  - u layout pairs batches: uint4 = {b even uint2, b odd uint2} -> 4
//    dwordx4 stores (was 8 dwordx2). K2 reads uint4 (half the loads, same
//    bytes) and routes 2 batches per block.
// W stays asm-pinned (32 VGPR). Fallback: round-10 fused kernel.

#define B_ 256
#define C_ 10
#define R_ 1152
#define I_ 8
#define O_ 16
#define T_ 512
#define KPT 9            // R chunks of 128
#define NW 8
#define NITER 3

typedef float f32x4 __attribute__((ext_vector_type(4)));

__device__ __forceinline__ uint32_t bf16_rn(float f) {
    uint32_t u = __builtin_bit_cast(uint32_t, f);
    return (u + 0x7FFFu + ((u >> 16) & 1u)) >> 16;
}
__device__ __forceinline__ uint32_t pack2(float lo, float hi) {
    return bf16_rn(lo) | (bf16_rn(hi) << 16);
}
__device__ __forceinline__ float unlo(uint32_t p) {
    return __builtin_bit_cast(float, p << 16);
}
__device__ __forceinline__ float unhi(uint32_t p) {
    return __builtin_bit_cast(float, p & 0xFFFF0000u);
}

// ---------------- K1: u[b,c,r,:] = x[b,r,:] @ W[c,r,:,:]  (bf16 packed) ----
// grid 2880 = c(10) x kchunk(9) x btile(32); 8 batches per block.
// u layout (uint4 units): (((b2*C + c)*KPT + kc)*512 + tid), b2 = b>>1;
//   .xy = batch 2*b2, .zw = batch 2*b2+1  (each uint2 = 4 bf16 outputs of oq).
__global__ __launch_bounds__(T_, 3) void caps_u_kernel(
    const float* __restrict__ x,
    const float* __restrict__ w,
    uint4* __restrict__ u)
{
    const int bx  = blockIdx.x;
    const int c   = bx / 288;
    const int kc  = (bx % 288) >> 5;
    const int bt  = bx & 31;
    const int b0  = bt * 8;
    const int tid = threadIdx.x;
    const int oq  = tid & 3;
    const int rl  = tid >> 2;
    const int r   = kc * 128 + rl;

    __shared__ float xs[8 * 1024];   // [bb][rl][8] compact, 32 KB

    // ---- stage x tile: 8 coalesced dwordx4 loads per thread ----
    {
        const float* xg = x + (size_t)b0 * (R_ * I_) + kc * 1024;  // row stride 9216 floats
        #pragma unroll
        for (int j = 0; j < 8; ++j) {
            const int e  = j * 512 + tid;       // 16B-unit index in [0,4096)
            const int bb = e >> 8;
            const int q  = e & 255;
            const float4 v = *(const float4*)(xg + (size_t)bb * (R_ * I_) + q * 4);
            *(float4*)&xs[e * 4] = v;
        }
    }

    // ---- W row-quad pinned in 32 VGPRs via asm loads ----
    const float* wbase = w + ((size_t)c * R_ + r) * (I_ * O_) + oq * 4;
    f32x4 W0, W1, W2, W3, W4, W5, W6, W7;
    asm volatile("global_load_dwordx4 %0, %1, off"            : "=v"(W0) : "v"(wbase));
    asm volatile("global_load_dwordx4 %0, %1, off offset:64"  : "=v"(W1) : "v"(wbase));
    asm volatile("global_load_dwordx4 %0, %1, off offset:128" : "=v"(W2) : "v"(wbase));
    asm volatile("global_load_dwordx4 %0, %1, off offset:192" : "=v"(W3) : "v"(wbase));
    asm volatile("global_load_dwordx4 %0, %1, off offset:256" : "=v"(W4) : "v"(wbase));
    asm volatile("global_load_dwordx4 %0, %1, off offset:320" : "=v"(W5) : "v"(wbase));
    asm volatile("global_load_dwordx4 %0, %1, off offset:384" : "=v"(W6) : "v"(wbase));
    asm volatile("global_load_dwordx4 %0, %1, off offset:448" : "=v"(W7) : "v"(wbase));
    asm volatile("s_waitcnt vmcnt(0)"
                 : "+v"(W0), "+v"(W1), "+v"(W2), "+v"(W3),
                   "+v"(W4), "+v"(W5), "+v"(W6), "+v"(W7));

    __syncthreads();   // x tile staged

    const size_t ubase = (((size_t)(bt * 4) * C_ + c) * KPT + kc) * T_ + tid;  // b2 = bt*4+p

    #pragma unroll
    for (int p = 0; p < 4; ++p) {      // batch pairs
        uint32_t lo0, lo1, hi0, hi1;
        #pragma unroll
        for (int h = 0; h < 2; ++h) {  // even/odd batch of the pair
            const int bb = p * 2 + h;
            const float4 xa = *(const float4*)&xs[(bb * 128 + rl) * 8];
            const float4 xb = *(const float4*)&xs[(bb * 128 + rl) * 8 + 4];
            float a0, a1, a2, a3;
            a0 = xa.x * W0[0]; a1 = xa.x * W0[1]; a2 = xa.x * W0[2]; a3 = xa.x * W0[3];
            a0 += xa.y * W1[0]; a1 += xa.y * W1[1]; a2 += xa.y * W1[2]; a3 += xa.y * W1[3];
            a0 += xa.z * W2[0]; a1 += xa.z * W2[1]; a2 += xa.z * W2[2]; a3 += xa.z * W2[3];
            a0 += xa.w * W3[0]; a1 += xa.w * W3[1]; a2 += xa.w * W3[2]; a3 += xa.w * W3[3];
            a0 += xb.x * W4[0]; a1 += xb.x * W4[1]; a2 += xb.x * W4[2]; a3 += xb.x * W4[3];
            a0 += xb.y * W5[0]; a1 += xb.y * W5[1]; a2 += xb.y * W5[2]; a3 += xb.y * W5[3];
            a0 += xb.z * W6[0]; a1 += xb.z * W6[1]; a2 += xb.z * W6[2]; a3 += xb.z * W6[3];
            a0 += xb.w * W7[0]; a1 += xb.w * W7[1]; a2 += xb.w * W7[2]; a3 += xb.w * W7[3];
            if (h == 0) { lo0 = pack2(a0, a1); lo1 = pack2(a2, a3); }
            else        { hi0 = pack2(a0, a1); hi1 = pack2(a2, a3); }
        }
        u[ubase + (size_t)p * (C_ * KPT * T_)] = make_uint4(lo0, lo1, hi0, hi1);
    }
}

// ---------------- K2: routing from materialized u (2 batches/block) -------
// block wg2 = b2*C + c (1280 blocks). Thread loads 9 uint4 (both batches'
// 36 bf16 u-values each). vsum trick: logit = u . (running sum of v).
__global__ __launch_bounds__(T_, 3) void caps_route_kernel(
    const uint4* __restrict__ u,
    float* __restrict__ out)
{
    const int wg2  = blockIdx.x;       // = b2*C + c
    const int b2   = wg2 / C_;
    const int c    = wg2 % C_;
    const int tid  = threadIdx.x;
    const int lane = tid & 63;
    const int wid  = tid >> 6;
    const int oq   = tid & 3;

    __shared__ float sred[2][NW][4][4];
    __shared__ float zred[2][NW];
    __shared__ float vsum[2][O_];

    uint4 up[KPT];
    #pragma unroll
    for (int k = 0; k < KPT; ++k)
        up[k] = u[((size_t)wg2 * KPT + k) * T_ + tid];

    if (tid < 2 * O_) vsum[tid >> 4][tid & 15] = 0.f;
    __syncthreads();

    #pragma unroll
    for (int it = 0; it < NITER; ++it) {
        float4 vs0 = make_float4(0.f, 0.f, 0.f, 0.f);
        float4 vs1 = vs0;
        if (it > 0) {
            vs0 = *(const float4*)&vsum[0][oq * 4];
            vs1 = *(const float4*)&vsum[1][oq * 4];
        }
        float z0 = 0.f, s00 = 0.f, s01 = 0.f, s02 = 0.f, s03 = 0.f;
        float z1 = 0.f, s10 = 0.f, s11 = 0.f, s12 = 0.f, s13 = 0.f;
        #pragma unroll
        for (int k = 0; k < KPT; ++k) {
            const float u00 = unlo(up[k].x), u01 = unhi(up[k].x);
            const float u02 = unlo(up[k].y), u03 = unhi(up[k].y);
            const float u10 = unlo(up[k].z), u11 = unhi(up[k].z);
            const float u12 = unlo(up[k].w), u13 = unhi(up[k].w);
            float e0, e1;
            if (it == 0) {
                e0 = 1.f; e1 = 1.f;
            } else {
                float d0 = u00 * vs0.x + u01 * vs0.y + u02 * vs0.z + u03 * vs0.w;
                float d1 = u10 * vs1.x + u11 * vs1.y + u12 * vs1.z + u13 * vs1.w;
                d0 += __shfl_xor(d0, 1); d1 += __shfl_xor(d1, 1);
                d0 += __shfl_xor(d0, 2); d1 += __shfl_xor(d1, 2);
                e0 = __expf(d0); e1 = __expf(d1);
            }
            z0 += e0; s00 += e0 * u00; s01 += e0 * u01; s02 += e0 * u02; s03 += e0 * u03;
            z1 += e1; s10 += e1 * u10; s11 += e1 * u11; s12 += e1 * u12; s13 += e1 * u13;
        }
        #pragma unroll
        for (int off = 4; off <= 32; off <<= 1) {
            z0 += __shfl_xor(z0, off);   z1 += __shfl_xor(z1, off);
            s00 += __shfl_xor(s00, off); s01 += __shfl_xor(s01, off);
            s02 += __shfl_xor(s02, off); s03 += __shfl_xor(s03, off);
            s10 += __shfl_xor(s10, off); s11 += __shfl_xor(s11, off);
            s12 += __shfl_xor(s12, off); s13 += __shfl_xor(s13, off);
        }
        if (lane < 4) {   // lane == oq
            sred[0][wid][lane][0] = s00; sred[0][wid][lane][1] = s01;
            sred[0][wid][lane][2] = s02; sred[0][wid][lane][3] = s03;
            sred[1][wid][lane][0] = s10; sred[1][wid][lane][1] = s11;
            sred[1][wid][lane][2] = s12; sred[1][wid][lane][3] = s13;
            if (lane == 0) { zred[0][wid] = z0; zred[1][wid] = z1; }
        }
        __syncthreads();

        // wave 0 finalizes both batches: lanes 0-15 -> even b, 16-31 -> odd b
        if (wid == 0 && lane < 2 * O_) {
            const int bb = lane >> 4;
            const int o  = lane & 15;
            float S = 0.f, Z = 0.f;
            #pragma unroll
            for (int wv = 0; wv < NW; ++wv) {
                S += sred[bb][wv][o >> 2][o & 3];
                Z += zred[bb][wv];
            }
            const float inv = 1.f / Z;
            const float svn = S * inv;
            float p = svn * svn;   // butterfly within 16-lane group -> |s|^2
            p += __shfl_xor(p, 1);
            p += __shfl_xor(p, 2);
            p += __shfl_xor(p, 4);
            p += __shfl_xor(p, 8);
            const float scale = sqrtf(p) / (1.f + p);
            const float vf = svn * scale;
            vsum[bb][o] += vf;
            if (it == NITER - 1)
                out[((size_t)(b2 * 2 + bb) * C_ + c) * O_ + o] = vf;
        }
        if (it != NITER - 1) __syncthreads();
    }
}

// ---------------- Fallback: round-10 fused kernel (proven) ----------------
#define BPB 4
#define RPP 128

__global__ __launch_bounds__(T_, 2) void capsule_fused_kernel(
    const float* __restrict__ x,
    const float* __restrict__ w,
    float* __restrict__ out)
{
    const int wg   = blockIdx.x;
    const int c    = wg >> 6;
    const int b0   = (wg & 63) * BPB;
    const int tid  = threadIdx.x;
    const int lane = tid & 63;
    const int wid  = tid >> 6;
    const int oq   = tid & 3;
    const int rl   = tid >> 2;

    __shared__ float sred[BPB][NW][4][4];
    __shared__ float zred[BPB][NW];
    __shared__ float vsum[BPB][O_];

    uint32_t up[BPB][KPT][2];

    if (tid < BPB * O_) vsum[tid >> 4][tid & 15] = 0.f;

    #pragma unroll
    for (int k = 0; k < KPT; ++k) {
        const int r = k * RPP + rl;
        const float4* wb4 = (const float4*)(w + ((size_t)c * R_ + r) * (I_ * O_));
        float4 W0 = wb4[0 * 4 + oq], W1 = wb4[1 * 4 + oq];
        float4 W2 = wb4[2 * 4 + oq], W3 = wb4[3 * 4 + oq];
        float4 W4 = wb4[4 * 4 + oq], W5 = wb4[5 * 4 + oq];
        float4 W6 = wb4[6 * 4 + oq], W7 = wb4[7 * 4 + oq];
        #pragma unroll
        for (int bb = 0; bb < BPB; ++bb) {
            const float4* xp = (const float4*)(x + ((size_t)(b0 + bb) * R_ + r) * I_);
            const float4 xa = xp[0];
            const float4 xb = xp[1];
            float a0, a1, a2, a3;
            a0 = xa.x * W0.x; a1 = xa.x * W0.y; a2 = xa.x * W0.z; a3 = xa.x * W0.w;
            a0 += xa.y * W1.x; a1 += xa.y * W1.y; a2 += xa.y * W1.z; a3 += xa.y * W1.w;
            a0 += xa.z * W2.x; a1 += xa.z * W2.y; a2 += xa.z * W2.z; a3 += xa.z * W2.w;
            a0 += xa.w * W3.x; a1 += xa.w * W3.y; a2 += xa.w * W3.z; a3 += xa.w * W3.w;
            a0 += xb.x * W4.x; a1 += xb.x * W4.y; a2 += xb.x * W4.z; a3 += xb.x * W4.w;
            a0 += xb.y * W5.x; a1 += xb.y * W5.y; a2 += xb.y * W5.z; a3 += xb.y * W5.w;
            a0 += xb.z * W6.x; a1 += xb.z * W6.y; a2 += xb.z * W6.z; a3 += xb.z * W6.w;
            a0 += xb.w * W7.x; a1 += xb.w * W7.y; a2 += xb.w * W7.z; a3 += xb.w * W7.w;
            up[bb][k][0] = pack2(a0, a1);
            up[bb][k][1] = pack2(a2, a3);
        }
    }
    __syncthreads();

    #pragma unroll
    for (int it = 0; it < NITER; ++it) {
        float zz[BPB], ss[BPB][4];
        #pragma unroll
        for (int bb = 0; bb < BPB; ++bb) {
            float4 vs = make_float4(0.f, 0.f, 0.f, 0.f);
            if (it > 0) vs = *(const float4*)&vsum[bb][oq * 4];
            float z = 0.f, s0 = 0.f, s1 = 0.f, s2 = 0.f, s3 = 0.f;
            #pragma unroll
            for (int k = 0; k < KPT; ++k) {
                const float u0 = unlo(up[bb][k][0]);
                const float u1 = unhi(up[bb][k][0]);
                const float u2 = unlo(up[bb][k][1]);
                const float u3 = unhi(up[bb][k][1]);
                float e;
                if (it == 0) {
                    e = 1.f;
                } else {
                    float d = u0 * vs.x + u1 * vs.y + u2 * vs.z + u3 * vs.w;
                    d += __shfl_xor(d, 1);
                    d += __shfl_xor(d, 2);
                    e = __expf(d);
                }
                z += e;
                s0 += e * u0; s1 += e * u1; s2 += e * u2; s3 += e * u3;
            }
            zz[bb] = z;
            ss[bb][0] = s0; ss[bb][1] = s1; ss[bb][2] = s2; ss[bb][3] = s3;
        }
        #pragma unroll
        for (int off = 4; off <= 32; off <<= 1) {
            #pragma unroll
            for (int bb = 0; bb < BPB; ++bb) {
                zz[bb] += __shfl_xor(zz[bb], off);
                ss[bb][0] += __shfl_xor(ss[bb][0], off);
                ss[bb][1] += __shfl_xor(ss[bb][1], off);
                ss[bb][2] += __shfl_xor(ss[bb][2], off);
                ss[bb][3] += __shfl_xor(ss[bb][3], off);
            }
        }
        if (lane < 4) {
            #pragma unroll
            for (int bb = 0; bb < BPB; ++bb) {
                sred[bb][wid][lane][0] = ss[bb][0];
                sred[bb][wid][lane][1] = ss[bb][1];
                sred[bb][wid][lane][2] = ss[bb][2];
                sred[bb][wid][lane][3] = ss[bb][3];
                if (lane == 0) zred[bb][wid] = zz[bb];
            }
        }
        __syncthreads();

        if (wid == 0) {
            const int bb = lane >> 4;
            const int o  = lane & 15;
            float S = 0.f, Z = 0.f;
            #pragma unroll
            for (int wv = 0; wv < NW; ++wv) {
                S += sred[bb][wv][o >> 2][o & 3];
                Z += zred[bb][wv];
            }
            const float inv = 1.f / Z;
            const float svn = S * inv;
            float p = svn * svn;
            p += __shfl_xor(p, 1);
            p += __shfl_xor(p, 2);
            p += __shfl_xor(p, 4);
            p += __shfl_xor(p, 8);
            const float scale = sqrtf(p) / (1.f + p);
            const float vf = svn * scale;
            vsum[bb][o] += vf;
            if (it == NITER - 1)
                out[((size_t)(b0 + bb) * C_ + c) * O_ + o] = vf;
        }
        if (it != NITER - 1) __syncthreads();
    }
}

extern "C" void kernel_launch(void* const* d_in, const int* in_sizes, int n_in,
                              void* d_out, int out_size, void* d_ws, size_t ws_size,
                              hipStream_t stream) {
    const float* x = (const float*)d_in[0];
    const float* w = (const float*)d_in[1];
    float* out = (float*)d_out;

    const size_t u_bytes = (size_t)(B_ / 2) * C_ * KPT * T_ * 16;   // 94,371,840
    if (ws_size >= u_bytes) {
        uint4* u = (uint4*)d_ws;
        caps_u_kernel<<<dim3(C_ * KPT * 32), dim3(T_), 0, stream>>>(x, w, u);
        caps_route_kernel<<<dim3((B_ / 2) * C_), dim3(T_), 0, stream>>>(u, out);
    } else {
        capsule_fused_kernel<<<dim3(C_ * (B_ / BPB)), dim3(T_), 0, stream>>>(x, w, out);
    }
}

// Round 17
// 61.257 us; speedup vs baseline: 1.0956x; 1.0956x over previous
//
#include <hip/hip_runtime.h>
#include <stdint.h>

// CapsuleLayer dynamic routing — round 17: round-16 with compile fix
// (nontemporal builtins need ext_vector_type, not HIP_vector_type uint4).
// x: [B=256, R=1152, I=8] f32; W: [C=10, R=1152, I=8, O=16] f32
// out: v = [B, C, 1, 1, O=16] f32
//
// K1 = r13 shape (plain float4 loads, FETCH 33MB) + paired u32x4 stores
// (4 stores/thread) + LB(512,4) (occupancy 62% -> ~100%) + NON-TEMPORAL u
// stores (no reuse in K1; keep the 94MB stream out of L2 so it doesn't
// evict x/W). K2 = 2-batch u32x4 routing + nontemporal u loads.
// Fallback: round-10 fused kernel if ws too small.

#define B_ 256
#define C_ 10
#define R_ 1152
#define I_ 8
#define O_ 16
#define T_ 512
#define KPT 9            // R chunks of 128
#define NW 8
#define NITER 3

typedef unsigned int u32x4 __attribute__((ext_vector_type(4)));

__device__ __forceinline__ uint32_t bf16_rn(float f) {
    uint32_t u = __builtin_bit_cast(uint32_t, f);
    return (u + 0x7FFFu + ((u >> 16) & 1u)) >> 16;
}
__device__ __forceinline__ uint32_t pack2(float lo, float hi) {
    return bf16_rn(lo) | (bf16_rn(hi) << 16);
}
__device__ __forceinline__ float unlo(uint32_t p) {
    return __builtin_bit_cast(float, p << 16);
}
__device__ __forceinline__ float unhi(uint32_t p) {
    return __builtin_bit_cast(float, p & 0xFFFF0000u);
}

// ---------------- K1: u[b,c,r,:] = x[b,r,:] @ W[c,r,:,:]  (bf16 packed) ----
// grid 2880 = c(10) x kchunk(9) x btile(32); 8 batches per block.
// u layout (u32x4 units): (((b2*C + c)*KPT + kc)*512 + tid), b2 = b>>1;
//   [0..1] = even batch, [2..3] = odd batch (each pair = 4 bf16 of oq).
__global__ __launch_bounds__(T_, 4) void caps_u_kernel(
    const float* __restrict__ x,
    const float* __restrict__ w,
    u32x4* __restrict__ u)
{
    const int bx  = blockIdx.x;
    const int c   = bx / 288;
    const int kc  = (bx % 288) >> 5;
    const int bt  = bx & 31;
    const int b0  = bt * 8;
    const int tid = threadIdx.x;
    const int oq  = tid & 3;
    const int rl  = tid >> 2;
    const int r   = kc * 128 + rl;

    const float4* wb4 = (const float4*)(w + ((size_t)c * R_ + r) * (I_ * O_));
    const float4 W0 = wb4[0 * 4 + oq], W1 = wb4[1 * 4 + oq];
    const float4 W2 = wb4[2 * 4 + oq], W3 = wb4[3 * 4 + oq];
    const float4 W4 = wb4[4 * 4 + oq], W5 = wb4[5 * 4 + oq];
    const float4 W6 = wb4[6 * 4 + oq], W7 = wb4[7 * 4 + oq];

    #pragma unroll
    for (int p = 0; p < 4; ++p) {      // batch pairs
        u32x4 q;
        #pragma unroll
        for (int h = 0; h < 2; ++h) {  // even/odd batch of the pair
            const int b = b0 + p * 2 + h;
            const float4* xp = (const float4*)(x + ((size_t)b * R_ + r) * I_);
            const float4 xa = xp[0];
            const float4 xb = xp[1];
            float a0, a1, a2, a3;
            a0 = xa.x * W0.x; a1 = xa.x * W0.y; a2 = xa.x * W0.z; a3 = xa.x * W0.w;
            a0 += xa.y * W1.x; a1 += xa.y * W1.y; a2 += xa.y * W1.z; a3 += xa.y * W1.w;
            a0 += xa.z * W2.x; a1 += xa.z * W2.y; a2 += xa.z * W2.z; a3 += xa.z * W2.w;
            a0 += xa.w * W3.x; a1 += xa.w * W3.y; a2 += xa.w * W3.z; a3 += xa.w * W3.w;
            a0 += xb.x * W4.x; a1 += xb.x * W4.y; a2 += xb.x * W4.z; a3 += xb.x * W4.w;
            a0 += xb.y * W5.x; a1 += xb.y * W5.y; a2 += xb.y * W5.z; a3 += xb.y * W5.w;
            a0 += xb.z * W6.x; a1 += xb.z * W6.y; a2 += xb.z * W6.z; a3 += xb.z * W6.w;
            a0 += xb.w * W7.x; a1 += xb.w * W7.y; a2 += xb.w * W7.z; a3 += xb.w * W7.w;
            q[h * 2 + 0] = pack2(a0, a1);
            q[h * 2 + 1] = pack2(a2, a3);
        }
        const size_t ui = (((size_t)(bt * 4 + p) * C_ + c) * KPT + kc) * T_ + tid;
        __builtin_nontemporal_store(q, &u[ui]);
    }
}

// ---------------- K2: routing from materialized u (2 batches/block) -------
// block wg2 = b2*C + c (1280 blocks). Thread loads 9 u32x4 (36 bf16 per
// batch). vsum trick: logit = u . (running sum of v); exp(0)=1 at it0.
__global__ __launch_bounds__(T_, 3) void caps_route_kernel(
    const u32x4* __restrict__ u,
    float* __restrict__ out)
{
    const int wg2  = blockIdx.x;       // = b2*C + c
    const int b2   = wg2 / C_;
    const int c    = wg2 % C_;
    const int tid  = threadIdx.x;
    const int lane = tid & 63;
    const int wid  = tid >> 6;
    const int oq   = tid & 3;

    __shared__ float sred[2][NW][4][4];
    __shared__ float zred[2][NW];
    __shared__ float vsum[2][O_];

    u32x4 up[KPT];
    #pragma unroll
    for (int k = 0; k < KPT; ++k)
        up[k] = __builtin_nontemporal_load(&u[((size_t)wg2 * KPT + k) * T_ + tid]);

    if (tid < 2 * O_) vsum[tid >> 4][tid & 15] = 0.f;
    __syncthreads();

    #pragma unroll
    for (int it = 0; it < NITER; ++it) {
        float4 vs0 = make_float4(0.f, 0.f, 0.f, 0.f);
        float4 vs1 = vs0;
        if (it > 0) {
            vs0 = *(const float4*)&vsum[0][oq * 4];
            vs1 = *(const float4*)&vsum[1][oq * 4];
        }
        float z0 = 0.f, s00 = 0.f, s01 = 0.f, s02 = 0.f, s03 = 0.f;
        float z1 = 0.f, s10 = 0.f, s11 = 0.f, s12 = 0.f, s13 = 0.f;
        #pragma unroll
        for (int k = 0; k < KPT; ++k) {
            const float u00 = unlo(up[k][0]), u01 = unhi(up[k][0]);
            const float u02 = unlo(up[k][1]), u03 = unhi(up[k][1]);
            const float u10 = unlo(up[k][2]), u11 = unhi(up[k][2]);
            const float u12 = unlo(up[k][3]), u13 = unhi(up[k][3]);
            float e0, e1;
            if (it == 0) {
                e0 = 1.f; e1 = 1.f;
            } else {
                float d0 = u00 * vs0.x + u01 * vs0.y + u02 * vs0.z + u03 * vs0.w;
                float d1 = u10 * vs1.x + u11 * vs1.y + u12 * vs1.z + u13 * vs1.w;
                d0 += __shfl_xor(d0, 1); d1 += __shfl_xor(d1, 1);
                d0 += __shfl_xor(d0, 2); d1 += __shfl_xor(d1, 2);
                e0 = __expf(d0); e1 = __expf(d1);
            }
            z0 += e0; s00 += e0 * u00; s01 += e0 * u01; s02 += e0 * u02; s03 += e0 * u03;
            z1 += e1; s10 += e1 * u10; s11 += e1 * u11; s12 += e1 * u12; s13 += e1 * u13;
        }
        #pragma unroll
        for (int off = 4; off <= 32; off <<= 1) {
            z0 += __shfl_xor(z0, off);   z1 += __shfl_xor(z1, off);
            s00 += __shfl_xor(s00, off); s01 += __shfl_xor(s01, off);
            s02 += __shfl_xor(s02, off); s03 += __shfl_xor(s03, off);
            s10 += __shfl_xor(s10, off); s11 += __shfl_xor(s11, off);
            s12 += __shfl_xor(s12, off); s13 += __shfl_xor(s13, off);
        }
        if (lane < 4) {   // lane == oq
            sred[0][wid][lane][0] = s00; sred[0][wid][lane][1] = s01;
            sred[0][wid][lane][2] = s02; sred[0][wid][lane][3] = s03;
            sred[1][wid][lane][0] = s10; sred[1][wid][lane][1] = s11;
            sred[1][wid][lane][2] = s12; sred[1][wid][lane][3] = s13;
            if (lane == 0) { zred[0][wid] = z0; zred[1][wid] = z1; }
        }
        __syncthreads();

        // wave 0 finalizes both batches: lanes 0-15 -> even b, 16-31 -> odd b
        if (wid == 0 && lane < 2 * O_) {
            const int bb = lane >> 4;
            const int o  = lane & 15;
            float S = 0.f, Z = 0.f;
            #pragma unroll
            for (int wv = 0; wv < NW; ++wv) {
                S += sred[bb][wv][o >> 2][o & 3];
                Z += zred[bb][wv];
            }
            const float inv = 1.f / Z;
            const float svn = S * inv;
            float p = svn * svn;   // butterfly within 16-lane group -> |s|^2
            p += __shfl_xor(p, 1);
            p += __shfl_xor(p, 2);
            p += __shfl_xor(p, 4);
            p += __shfl_xor(p, 8);
            const float scale = sqrtf(p) / (1.f + p);
            const float vf = svn * scale;
            vsum[bb][o] += vf;
            if (it == NITER - 1)
                out[((size_t)(b2 * 2 + bb) * C_ + c) * O_ + o] = vf;
        }
        if (it != NITER - 1) __syncthreads();
    }
}

// ---------------- Fallback: round-10 fused kernel (proven) ----------------
#define BPB 4
#define RPP 128

__global__ __launch_bounds__(T_, 2) void capsule_fused_kernel(
    const float* __restrict__ x,
    const float* __restrict__ w,
    float* __restrict__ out)
{
    const int wg   = blockIdx.x;
    const int c    = wg >> 6;
    const int b0   = (wg & 63) * BPB;
    const int tid  = threadIdx.x;
    const int lane = tid & 63;
    const int wid  = tid >> 6;
    const int oq   = tid & 3;
    const int rl   = tid >> 2;

    __shared__ float sred[BPB][NW][4][4];
    __shared__ float zred[BPB][NW];
    __shared__ float vsum[BPB][O_];

    uint32_t up[BPB][KPT][2];

    if (tid < BPB * O_) vsum[tid >> 4][tid & 15] = 0.f;

    #pragma unroll
    for (int k = 0; k < KPT; ++k) {
        const int r = k * RPP + rl;
        const float4* wb4 = (const float4*)(w + ((size_t)c * R_ + r) * (I_ * O_));
        float4 W0 = wb4[0 * 4 + oq], W1 = wb4[1 * 4 + oq];
        float4 W2 = wb4[2 * 4 + oq], W3 = wb4[3 * 4 + oq];
        float4 W4 = wb4[4 * 4 + oq], W5 = wb4[5 * 4 + oq];
        float4 W6 = wb4[6 * 4 + oq], W7 = wb4[7 * 4 + oq];
        #pragma unroll
        for (int bb = 0; bb < BPB; ++bb) {
            const float4* xp = (const float4*)(x + ((size_t)(b0 + bb) * R_ + r) * I_);
            const float4 xa = xp[0];
            const float4 xb = xp[1];
            float a0, a1, a2, a3;
            a0 = xa.x * W0.x; a1 = xa.x * W0.y; a2 = xa.x * W0.z; a3 = xa.x * W0.w;
            a0 += xa.y * W1.x; a1 += xa.y * W1.y; a2 += xa.y * W1.z; a3 += xa.y * W1.w;
            a0 += xa.z * W2.x; a1 += xa.z * W2.y; a2 += xa.z * W2.z; a3 += xa.z * W2.w;
            a0 += xa.w * W3.x; a1 += xa.w * W3.y; a2 += xa.w * W3.z; a3 += xa.w * W3.w;
            a0 += xb.x * W4.x; a1 += xb.x * W4.y; a2 += xb.x * W4.z; a3 += xb.x * W4.w;
            a0 += xb.y * W5.x; a1 += xb.y * W5.y; a2 += xb.y * W5.z; a3 += xb.y * W5.w;
            a0 += xb.z * W6.x; a1 += xb.z * W6.y; a2 += xb.z * W6.z; a3 += xb.z * W6.w;
            a0 += xb.w * W7.x; a1 += xb.w * W7.y; a2 += xb.w * W7.z; a3 += xb.w * W7.w;
            up[bb][k][0] = pack2(a0, a1);
            up[bb][k][1] = pack2(a2, a3);
        }
    }
    __syncthreads();

    #pragma unroll
    for (int it = 0; it < NITER; ++it) {
        float zz[BPB], ss[BPB][4];
        #pragma unroll
        for (int bb = 0; bb < BPB; ++bb) {
            float4 vs = make_float4(0.f, 0.f, 0.f, 0.f);
            if (it > 0) vs = *(const float4*)&vsum[bb][oq * 4];
            float z = 0.f, s0 = 0.f, s1 = 0.f, s2 = 0.f, s3 = 0.f;
            #pragma unroll
            for (int k = 0; k < KPT; ++k) {
                const float u0 = unlo(up[bb][k][0]);
                const float u1 = unhi(up[bb][k][0]);
                const float u2 = unlo(up[bb][k][1]);
                const float u3 = unhi(up[bb][k][1]);
                float e;
                if (it == 0) {
                    e = 1.f;
                } else {
                    float d = u0 * vs.x + u1 * vs.y + u2 * vs.z + u3 * vs.w;
                    d += __shfl_xor(d, 1);
                    d += __shfl_xor(d, 2);
                    e = __expf(d);
                }
                z += e;
                s0 += e * u0; s1 += e * u1; s2 += e * u2; s3 += e * u3;
            }
            zz[bb] = z;
            ss[bb][0] = s0; ss[bb][1] = s1; ss[bb][2] = s2; ss[bb][3] = s3;
        }
        #pragma unroll
        for (int off = 4; off <= 32; off <<= 1) {
            #pragma unroll
            for (int bb = 0; bb < BPB; ++bb) {
                zz[bb] += __shfl_xor(zz[bb], off);
                ss[bb][0] += __shfl_xor(ss[bb][0], off);
                ss[bb][1] += __shfl_xor(ss[bb][1], off);
                ss[bb][2] += __shfl_xor(ss[bb][2], off);
                ss[bb][3] += __shfl_xor(ss[bb][3], off);
            }
        }
        if (lane < 4) {
            #pragma unroll
            for (int bb = 0; bb < BPB; ++bb) {
                sred[bb][wid][lane][0] = ss[bb][0];
                sred[bb][wid][lane][1] = ss[bb][1];
                sred[bb][wid][lane][2] = ss[bb][2];
                sred[bb][wid][lane][3] = ss[bb][3];
                if (lane == 0) zred[bb][wid] = zz[bb];
            }
        }
        __syncthreads();

        if (wid == 0) {
            const int bb = lane >> 4;
            const int o  = lane & 15;
            float S = 0.f, Z = 0.f;
            #pragma unroll
            for (int wv = 0; wv < NW; ++wv) {
                S += sred[bb][wv][o >> 2][o & 3];
                Z += zred[bb][wv];
            }
            const float inv = 1.f / Z;
            const float svn = S * inv;
            float p = svn * svn;
            p += __shfl_xor(p, 1);
            p += __shfl_xor(p, 2);
            p += __shfl_xor(p, 4);
            p += __shfl_xor(p, 8);
            const float scale = sqrtf(p) / (1.f + p);
            const float vf = svn * scale;
            vsum[bb][o] += vf;
            if (it == NITER - 1)
                out[((size_t)(b0 + bb) * C_ + c) * O_ + o] = vf;
        }
        if (it != NITER - 1) __syncthreads();
    }
}

extern "C" void kernel_launch(void* const* d_in, const int* in_sizes, int n_in,
                              void* d_out, int out_size, void* d_ws, size_t ws_size,
                              hipStream_t stream) {
    const float* x = (const float*)d_in[0];
    const float* w = (const float*)d_in[1];
    float* out = (float*)d_out;

    const size_t u_bytes = (size_t)(B_ / 2) * C_ * KPT * T_ * 16;   // 94,371,840
    if (ws_size >= u_bytes) {
        u32x4* u = (u32x4*)d_ws;
        caps_u_kernel<<<dim3(C_ * KPT * 32), dim3(T_), 0, stream>>>(x, w, u);
        caps_route_kernel<<<dim3((B_ / 2) * C_), dim3(T_), 0, stream>>>(u, out);
    } else {
        capsule_fused_kernel<<<dim3(C_ * (B_ / BPB)), dim3(T_), 0, stream>>>(x, w, out);
    }
}